// Round 3
// baseline (604.339 us; speedup 1.0000x reference)
//
#include <hip/hip_runtime.h>
#include <cstdint>

#define S_TOKENS 16384
#define NEXP     8
#define CAP      2560
#define BLK      256
#define NBLK     (S_TOKENS / BLK)   // 64
#define NWAVE    (BLK / 64)         // 4
#define FILL_BLOCKS 2048

typedef unsigned int u32x4 __attribute__((ext_vector_type(4)));

// Kernel A: zero-fill the whole output (grid-stride 16B nt-stores).
// Blocks 0..63 additionally compute routing for their 256 tokens:
// top1 idx, softmax prob, within-block per-expert rank (ballot-based,
// deterministic), and per-block per-expert counts.
__global__ __launch_bounds__(BLK) void k_fill_route(const float* __restrict__ in,
                                                    float* __restrict__ prob,
                                                    int* __restrict__ packed,
                                                    int* __restrict__ block_counts,
                                                    u32x4* __restrict__ out4,
                                                    long n4) {
    if (blockIdx.x < NBLK) {
        int t = blockIdx.x * BLK + threadIdx.x;
        const float4* p4 = reinterpret_cast<const float4*>(in + (size_t)t * NEXP);
        float4 a = p4[0], b = p4[1];
        float x[8] = {a.x, a.y, a.z, a.w, b.x, b.y, b.z, b.w};

        // argmax, first-max wins (matches jnp.argmax)
        float m = x[0]; int idx = 0;
#pragma unroll
        for (int i = 1; i < 8; ++i) {
            if (x[i] > m) { m = x[i]; idx = i; }
        }
        // softmax prob of the top expert = 1 / sum(exp(x - max))
        float s = 0.f;
#pragma unroll
        for (int i = 0; i < 8; ++i) s += __expf(x[i] - m);
        float p = 1.0f / s;

        unsigned long long bal[NEXP];
#pragma unroll
        for (int e = 0; e < NEXP; ++e) bal[e] = __ballot(idx == e);

        int lane = threadIdx.x & 63;
        int wv   = threadIdx.x >> 6;

        __shared__ int wcnt[NWAVE][NEXP];
        if (lane < NEXP) wcnt[wv][lane] = __popcll(bal[lane]);
        __syncthreads();

        unsigned long long ltmask = (1ULL << lane) - 1ULL;
        int r = __popcll(bal[idx] & ltmask);
#pragma unroll
        for (int w = 0; w < NWAVE; ++w)
            if (w < wv) r += wcnt[w][idx];

        prob[t]   = p;
        packed[t] = (r << 3) | idx;

        if (threadIdx.x < NEXP) {
            int c = 0;
#pragma unroll
            for (int w = 0; w < NWAVE; ++w) c += wcnt[w][threadIdx.x];
            block_counts[blockIdx.x * NEXP + threadIdx.x] = c;
        }
    }

    // grid-stride zero fill, 16B per nt-store
    u32x4 z = (u32x4)(0u);
    long stride = (long)gridDim.x * (long)blockDim.x;
    for (long i = (long)blockIdx.x * BLK + threadIdx.x; i < n4; i += stride) {
        __builtin_nontemporal_store(z, &out4[i]);
    }
}

// Kernel B: per-token global rank via on-the-fly exclusive scan of the
// 64x8 block-count table (loaded to LDS), then scatter the nonzeros.
__global__ __launch_bounds__(BLK) void k_scatter(const float* __restrict__ prob,
                                                 const int* __restrict__ packed,
                                                 const int* __restrict__ block_counts,
                                                 float* __restrict__ out,
                                                 size_t mask_base) {
    __shared__ int sb[NBLK * NEXP];
    for (int i = threadIdx.x; i < NBLK * NEXP; i += BLK)
        sb[i] = block_counts[i];
    __syncthreads();

    int t = blockIdx.x * BLK + threadIdx.x;
    int pk  = packed[t];
    int idx = pk & 7;
    int g   = pk >> 3;
    for (int b = 0; b < blockIdx.x; ++b)
        g += sb[b * NEXP + idx];

    if (g < CAP) {
        size_t o = ((size_t)t * NEXP + idx) * CAP + (size_t)g;
        out[o] = prob[t];               // combine_weights
        out[mask_base + o] = 1.0f;      // sec_mask (bool as 0/1 float)
    }
}

extern "C" void kernel_launch(void* const* d_in, const int* in_sizes, int n_in,
                              void* d_out, int out_size, void* d_ws, size_t ws_size,
                              hipStream_t stream) {
    const float* in = (const float*)d_in[0];
    float* out = (float*)d_out;

    char* ws = (char*)d_ws;
    float* prob   = (float*)(ws);                    // 64 KB
    int*   packed = (int*)(ws + (64 << 10));         // 64 KB
    int*   bcnt   = (int*)(ws + (128 << 10));        // 2 KB

    long n4 = (long)out_size / 4;  // out_size divisible by 4

    k_fill_route<<<FILL_BLOCKS, BLK, 0, stream>>>(in, prob, packed, bcnt,
                                                  (u32x4*)out, n4);

    size_t mask_base = (size_t)out_size / 2;
    k_scatter<<<NBLK, BLK, 0, stream>>>(prob, packed, bcnt, out, mask_base);
}

// Round 4
// 561.372 us; speedup vs baseline: 1.0765x; 1.0765x over previous
//
#include <hip/hip_runtime.h>
#include <cstdint>

#define S_TOKENS 16384
#define NEXP     8
#define CAP      2560
#define BLK      256
#define NBLK     (S_TOKENS / BLK)   // 64
#define NWAVE    (BLK / 64)         // 4
#define FILL_BLOCKS 2048

typedef unsigned int u32x4 __attribute__((ext_vector_type(4)));

// Kernel A: zero-fill the whole output (grid-stride 16B stores).
// Blocks 0..63 additionally compute routing for their 256 tokens:
// top1 idx, softmax prob, within-block per-expert rank (ballot-based,
// deterministic), and per-block per-expert counts.
__global__ __launch_bounds__(BLK) void k_fill_route(const float* __restrict__ in,
                                                    float* __restrict__ prob,
                                                    int* __restrict__ packed,
                                                    int* __restrict__ block_counts,
                                                    u32x4* __restrict__ out4,
                                                    long n4) {
    if (blockIdx.x < NBLK) {
        int t = blockIdx.x * BLK + threadIdx.x;
        const float4* p4 = reinterpret_cast<const float4*>(in + (size_t)t * NEXP);
        float4 a = p4[0], b = p4[1];
        float x[8] = {a.x, a.y, a.z, a.w, b.x, b.y, b.z, b.w};

        // argmax, first-max wins (matches jnp.argmax)
        float m = x[0]; int idx = 0;
#pragma unroll
        for (int i = 1; i < 8; ++i) {
            if (x[i] > m) { m = x[i]; idx = i; }
        }
        // softmax prob of the top expert = 1 / sum(exp(x - max))
        float s = 0.f;
#pragma unroll
        for (int i = 0; i < 8; ++i) s += __expf(x[i] - m);
        float p = 1.0f / s;

        unsigned long long bal[NEXP];
#pragma unroll
        for (int e = 0; e < NEXP; ++e) bal[e] = __ballot(idx == e);

        int lane = threadIdx.x & 63;
        int wv   = threadIdx.x >> 6;

        __shared__ int wcnt[NWAVE][NEXP];
        if (lane < NEXP) wcnt[wv][lane] = __popcll(bal[lane]);
        __syncthreads();

        unsigned long long ltmask = (1ULL << lane) - 1ULL;
        int r = __popcll(bal[idx] & ltmask);
#pragma unroll
        for (int w = 0; w < NWAVE; ++w)
            if (w < wv) r += wcnt[w][idx];

        prob[t]   = p;
        packed[t] = (r << 3) | idx;

        if (threadIdx.x < NEXP) {
            int c = 0;
#pragma unroll
            for (int w = 0; w < NWAVE; ++w) c += wcnt[w][threadIdx.x];
            block_counts[blockIdx.x * NEXP + threadIdx.x] = c;
        }
    }

    // grid-stride zero fill, 16B per store (plain stores — nt regressed 38%)
    u32x4 z = (u32x4)(0u);
    long stride = (long)gridDim.x * (long)blockDim.x;
    for (long i = (long)blockIdx.x * BLK + threadIdx.x; i < n4; i += stride) {
        out4[i] = z;
    }
}

// Kernel B: per-token global rank via on-the-fly exclusive scan of the
// 64x8 block-count table (loaded to LDS), then scatter the nonzeros.
__global__ __launch_bounds__(BLK) void k_scatter(const float* __restrict__ prob,
                                                 const int* __restrict__ packed,
                                                 const int* __restrict__ block_counts,
                                                 float* __restrict__ out,
                                                 size_t mask_base) {
    __shared__ int sb[NBLK * NEXP];
    for (int i = threadIdx.x; i < NBLK * NEXP; i += BLK)
        sb[i] = block_counts[i];
    __syncthreads();

    int t = blockIdx.x * BLK + threadIdx.x;
    int pk  = packed[t];
    int idx = pk & 7;
    int g   = pk >> 3;
    for (int b = 0; b < blockIdx.x; ++b)
        g += sb[b * NEXP + idx];

    if (g < CAP) {
        size_t o = ((size_t)t * NEXP + idx) * CAP + (size_t)g;
        out[o] = prob[t];               // combine_weights
        out[mask_base + o] = 1.0f;      // sec_mask (bool as 0/1 float)
    }
}

extern "C" void kernel_launch(void* const* d_in, const int* in_sizes, int n_in,
                              void* d_out, int out_size, void* d_ws, size_t ws_size,
                              hipStream_t stream) {
    const float* in = (const float*)d_in[0];
    float* out = (float*)d_out;

    char* ws = (char*)d_ws;
    float* prob   = (float*)(ws);                    // 64 KB
    int*   packed = (int*)(ws + (64 << 10));         // 64 KB
    int*   bcnt   = (int*)(ws + (128 << 10));        // 2 KB

    long n4 = (long)out_size / 4;  // out_size divisible by 4

    k_fill_route<<<FILL_BLOCKS, BLK, 0, stream>>>(in, prob, packed, bcnt,
                                                  (u32x4*)out, n4);

    size_t mask_base = (size_t)out_size / 2;
    k_scatter<<<NBLK, BLK, 0, stream>>>(prob, packed, bcnt, out, mask_base);
}

// Round 5
// 435.251 us; speedup vs baseline: 1.3885x; 1.2898x over previous
//
#include <hip/hip_runtime.h>
#include <cstdint>

#define S_TOKENS 16384
#define NEXP     8
#define CAP      2560
#define BLK      256
#define NBLK     (S_TOKENS / BLK)   // 64
#define NWAVE    (BLK / 64)         // 4

// Kernel 1: per-token top1 + softmax prob + within-block per-expert rank,
// plus per-block per-expert counts. Deterministic (ballot-based, no atomics).
__global__ __launch_bounds__(BLK) void k_route(const float* __restrict__ in,
                                               float* __restrict__ prob,
                                               int* __restrict__ packed,
                                               int* __restrict__ block_counts) {
    int t = blockIdx.x * BLK + threadIdx.x;
    const float4* p4 = reinterpret_cast<const float4*>(in + (size_t)t * NEXP);
    float4 a = p4[0], b = p4[1];
    float x[8] = {a.x, a.y, a.z, a.w, b.x, b.y, b.z, b.w};

    // argmax, first-max wins (matches jnp.argmax)
    float m = x[0]; int idx = 0;
#pragma unroll
    for (int i = 1; i < 8; ++i) {
        if (x[i] > m) { m = x[i]; idx = i; }
    }
    // softmax prob of the top expert = 1 / sum(exp(x - max))
    float s = 0.f;
#pragma unroll
    for (int i = 0; i < 8; ++i) s += __expf(x[i] - m);
    float p = 1.0f / s;

    unsigned long long bal[NEXP];
#pragma unroll
    for (int e = 0; e < NEXP; ++e) bal[e] = __ballot(idx == e);

    int lane = threadIdx.x & 63;
    int wv   = threadIdx.x >> 6;

    __shared__ int wcnt[NWAVE][NEXP];
    if (lane < NEXP) wcnt[wv][lane] = __popcll(bal[lane]);
    __syncthreads();

    unsigned long long ltmask = (1ULL << lane) - 1ULL;
    int r = __popcll(bal[idx] & ltmask);
#pragma unroll
    for (int w = 0; w < NWAVE; ++w)
        if (w < wv) r += wcnt[w][idx];

    prob[t]   = p;
    packed[t] = (r << 3) | idx;

    if (threadIdx.x < NEXP) {
        int c = 0;
#pragma unroll
        for (int w = 0; w < NWAVE; ++w) c += wcnt[w][threadIdx.x];
        block_counts[blockIdx.x * NEXP + threadIdx.x] = c;
    }
}

// Kernel 2: per-token global rank via on-the-fly exclusive scan of the
// 64x8 block-count table (loaded to LDS), then scatter the nonzeros into
// the (memset-zeroed) output.
__global__ __launch_bounds__(BLK) void k_scatter(const float* __restrict__ prob,
                                                 const int* __restrict__ packed,
                                                 const int* __restrict__ block_counts,
                                                 float* __restrict__ out,
                                                 size_t mask_base) {
    __shared__ int sb[NBLK * NEXP];
    for (int i = threadIdx.x; i < NBLK * NEXP; i += BLK)
        sb[i] = block_counts[i];
    __syncthreads();

    int t = blockIdx.x * BLK + threadIdx.x;
    int pk  = packed[t];
    int idx = pk & 7;
    int g   = pk >> 3;
    for (int b = 0; b < blockIdx.x; ++b)
        g += sb[b * NEXP + idx];

    if (g < CAP) {
        size_t o = ((size_t)t * NEXP + idx) * CAP + (size_t)g;
        out[o] = prob[t];               // combine_weights
        out[mask_base + o] = 1.0f;      // sec_mask (bool as 0/1 float)
    }
}

extern "C" void kernel_launch(void* const* d_in, const int* in_sizes, int n_in,
                              void* d_out, int out_size, void* d_ws, size_t ws_size,
                              hipStream_t stream) {
    const float* in = (const float*)d_in[0];
    float* out = (float*)d_out;

    char* ws = (char*)d_ws;
    float* prob   = (float*)(ws);                    // 64 KB
    int*   packed = (int*)(ws + (64 << 10));         // 64 KB
    int*   bcnt   = (int*)(ws + (128 << 10));        // 2 KB

    // Routing first (touches only d_in / d_ws), then the big zero pass via
    // rocclr's fill (measured 6.35+ TB/s — beats our custom fill kernels),
    // then the tiny scatter.
    k_route<<<NBLK, BLK, 0, stream>>>(in, prob, packed, bcnt);

    hipMemsetAsync(d_out, 0, (size_t)out_size * sizeof(float), stream);

    size_t mask_base = (size_t)out_size / 2;
    k_scatter<<<NBLK, BLK, 0, stream>>>(prob, packed, bcnt, out, mask_base);
}